// Round 3
// baseline (404.390 us; speedup 1.0000x reference)
//
#include <hip/hip_runtime.h>
#include <hip/hip_bf16.h>

// Problem constants (SymNetDP): B=64, S=4096, NGB=13, NG=48, DIM=3, NCH={8,8,1}
#define BATCH 64
#define SITES 4096
#define NGB 13
#define NGRP 48
#define SDIM 3

typedef __bf16 bf16x8 __attribute__((ext_vector_type(8)));
typedef float  f32x4  __attribute__((ext_vector_type(4)));

// ---------------------------------------------------------------------------
// Workspace layout:
//   Avc  : 39 f32; QCTR: 24 i32 @ float 40 (pad to 64)   @ float 0
//   U    : bf16 region, 135168 elems            @ float 64
//     W0H [384][32] 12288 | W0L @12288 | W1H [384][128] @24576 (49152) |
//     W1L @73728 | W2H [48][128] @122880 (6144) | W2L @129024
//   A0   : (B,S,8) channel-last, 2097152 f32    @ float 67648  (A2 aliases)
//   A1   : (B,S,8) channel-last, 2097152 f32    @ float 2164800
//   PART : (64,16,3) 3072                       @ float 4261952
// K-packing for NCIN=8 layers: k = j*8 + c  (site's 8 channels contiguous).
// ---------------------------------------------------------------------------
#define OFF_AVC  0
#define OFF_QCTR 40
#define OFF_U    64
#define OFF_A0   67648
#define OFF_A1   2164800
#define OFF_PART 4261952
#define UW0H 0
#define UW0L 12288
#define UW1H 24576
#define UW1L 73728
#define UW2H 122880
#define UW2L 129024

__device__ __forceinline__ float softplus_f(float h) {
    return fmaxf(h, 0.f) + __logf(1.f + __expf(-fabsf(h)));
}

// Actual XCD id of the CU this block landed on (gfx940+; verified gfx950).
__device__ __forceinline__ int xcc_id() {
    int x;
    asm volatile("s_getreg_b32 %0, hwreg(HW_REG_XCC_ID, 0, 4)" : "=s"(x));
    return x & 7;
}

// ---------------------------------------------------------------------------
// Precompute: rotated weights, bf16 hi/lo split, [row=o*48+g][KPAD] with
// k = j*8+c packing for K=104 layers (k = j for layer 0); plus Avc.
// ---------------------------------------------------------------------------
__global__ __launch_bounds__(256) void precompute_kernel(
    const float* __restrict__ Psi0, const float* __restrict__ Psi1,
    const float* __restrict__ Psi2, const float* __restrict__ wtVC,
    const float* __restrict__ gdiags, const int* __restrict__ perms,
    float* __restrict__ ws)
{
    float*  Avc = ws + OFF_AVC;
    __bf16* U   = (__bf16*)(ws + OFF_U);
    int t = blockIdx.x * 256 + threadIdx.x;
    if (t < 12288) {                       // W0: [384][32], k=j
        int k = t & 31, row = t >> 5;
        int o = row / NGRP, g = row - o * NGRP;
        float w = (k < NGB) ? Psi0[o * NGB + perms[g * NGB + k]] : 0.f;
        __bf16 hi = (__bf16)w;
        U[UW0H + t] = hi;
        U[UW0L + t] = (__bf16)(w - (float)hi);
    } else if (t < 61440) {                // W1: [384][128], k=j*8+c
        int u = t - 12288;
        int k = u & 127, row = u >> 7;
        int o = row / NGRP, g = row - o * NGRP;
        float w = 0.f;
        if (k < 104) { int j = k >> 3, c = k & 7;
                       w = Psi1[(o * 8 + c) * NGB + perms[g * NGB + j]]; }
        __bf16 hi = (__bf16)w;
        U[UW1H + u] = hi;
        U[UW1L + u] = (__bf16)(w - (float)hi);
    } else if (t < 67584) {                // W2: [48][128], k=j*8+c
        int u = t - 61440;
        int k = u & 127, g = u >> 7;
        float w = 0.f;
        if (k < 104) { int j = k >> 3, c = k & 7;
                       w = Psi2[c * NGB + perms[g * NGB + j]]; }
        __bf16 hi = (__bf16)w;
        U[UW2H + u] = hi;
        U[UW2L + u] = (__bf16)(w - (float)hi);
    } else if (t < 67584 + 39 * NGRP) {    // Avc
        int t2 = t - 67584;
        int g = t2 % NGRP, u = t2 / NGRP;
        int d = u / NGB, n = u % NGB;
        const int row = g * SDIM + d;
        float s = 0.f;
        for (int k = 0; k < NGRP * SDIM; k++) {
            int g2 = k / SDIM, d2 = k - g2 * SDIM;
            float p = wtVC[d2 * NGB + perms[g2 * NGB + n]];
            s = fmaf(gdiags[row * (NGRP * SDIM) + k], p, s);
        }
        atomicAdd(&Avc[u], s * (1.f / 48.f));
    }
}

// ---------------------------------------------------------------------------
// MFMA gconv layer (bf16x3 split), v12: PERSISTENT + DOUBLE-BUFFERED +
// RUNTIME XCD WORK QUEUES.
// v11 post-mortem: the static `bid&7 -> XCD` guess is wrong on this chip's
// dispatcher (FETCH only dropped 24%; writes still 30x inflated = zero L2
// coalescing). v12 reads the REAL XCD id (s_getreg HW_REG_XCC_ID, m09) and
// pulls a (batch, octet) unit from a per-XCD atomic queue: XCD x serves
// batches [x*8, x*8+8) -> per-XCD L2 working set ~2.4 MB (< 4 MB), under
// ANY dispatch mapping. Batch->XCD pinning identical across L0/L1/L2 ->
// cross-dispatch slab reuse. Pigeonhole: 8 queues x 64 tickets = 512 =
// nblocks, overflow falls through to neighbor queues -> every block gets
// exactly one unit.
// Per iteration: issue gathers for chunk t+1 (NN prefetched 2 ahead),
// compute chunk t from buffer t&1, cvt+write chunk t+1 into buffer (t+1)&1,
// one barrier (T14 issue-early/write-late).
// ---------------------------------------------------------------------------
template<int NCIN, int NCTOT, int CT, int KPAD, int KSTR, int NWAVES, int NWN,
         int CHUNKS>
__global__ __launch_bounds__(NWAVES * 64, 4) void layer_mfma(
    const float* __restrict__ prev,   // (B,S) if NCIN==1 else (B,S,8)
    const __bf16* __restrict__ Wh,    // [NCTOT*48][KPAD]
    const __bf16* __restrict__ Wl,
    const float* __restrict__ bias,   // (NCTOT,)
    const int*   __restrict__ NN,     // (13, S)
    int*         __restrict__ qctr,   // 8 per-XCD queue counters (zeroed)
    float* __restrict__ out)          // (B,S,NCTOT) channel-last
{
    constexpr int NTHR   = NWAVES * 64;
    constexpr int M      = NCTOT * NGRP;
    constexpr int MTILES = M / 16, NTILES = CT / 16;
    constexpr int NWM    = NWAVES / NWN;
    constexpr int MT_W   = MTILES / NWM, NT_W = NTILES / NWN;
    constexpr int KT     = KPAD / 32;
    constexpr int GS     = NGB * CT;              // gathered sites per chunk
    constexpr int SPT    = (GS + NTHR - 1) / NTHR;
    constexpr int CPB    = SITES / CT;            // chunks per batch
    constexpr int BUF    = CT * KSTR;             // halfwords per LDS buffer
    constexpr int BPB    = CPB / CHUNKS;          // blocks per batch
    constexpr int NXCD   = 8;
    constexpr int BAT_X  = BATCH / NXCD;          // batches per XCD queue
    constexpr int UPQ    = BAT_X * BPB;           // work units per queue (64)

    static_assert(MT_W * 16 == NGRP, "wave covers exactly one o");
    static_assert(NWM * MT_W == MTILES && NWN * NT_W == NTILES, "");
    static_assert((KPAD & 31) == 0 && (KSTR & 7) == 0, "");
    static_assert(CPB % CHUNKS == 0, "block stays within one batch");
    static_assert(NXCD * UPQ == BATCH * BPB, "tickets == blocks");

    __shared__ __bf16 xh_lds[2 * BUF];
    __shared__ __bf16 xl_lds[2 * BUF];
    __shared__ int s_unit;

    const int tid  = threadIdx.x;
    const int wave = tid >> 6, lane = tid & 63;
    const int m16  = lane & 15, quad = lane >> 4;

    // --- grab a work unit from this block's ACTUAL XCD's queue --------------
    if (tid == 0) {
        int xcc = xcc_id();
        int unit = -1;
        for (int k = 0; k < NXCD; k++) {
            int q = (xcc + k) & (NXCD - 1);
            int idx = atomicAdd(&qctr[q], 1);
            if (idx < UPQ) { unit = q * UPQ + idx; break; }
        }
        s_unit = unit;
    }
    __syncthreads();
    const int unit = s_unit;
    if (unit < 0) return;                          // cannot happen (pigeonhole)
    const int q      = unit / UPQ;                 // actual XCD
    const int idx    = unit - q * UPQ;
    const int b      = q * BAT_X + idx / BPB;      // XCD q -> batches [q*8, q*8+8)
    const int octet  = idx % BPB;
    const int s0base = octet * (CHUNKS * CT);

    // --- per-thread staged-site slots (static decomposition) ----------------
    int sj[SPT], scol[SPT];
    bool sv[SPT];
#pragma unroll
    for (int i = 0; i < SPT; i++) {
        int site = tid + i * NTHR;
        sv[i] = (site < GS);
        int ss = sv[i] ? site : 0;
        sj[i] = ss / CT;
        scol[i] = ss % CT;
    }

    // --- zero the K-pad region of BOTH buffers once -------------------------
    if constexpr (NCIN == 1) {
        for (int e = tid; e < 2 * CT * (KPAD - NGB); e += NTHR) {
            int buf = e / (CT * (KPAD - NGB));
            int r   = e % (CT * (KPAD - NGB));
            int col = r / (KPAD - NGB), p = r % (KPAD - NGB);
            xh_lds[buf * BUF + col * KSTR + NGB + p] = (__bf16)0.f;
            xl_lds[buf * BUF + col * KSTR + NGB + p] = (__bf16)0.f;
        }
    } else {
        const bf16x8 z8 = {};
        for (int e = tid; e < 2 * CT * 3; e += NTHR) {
            int buf = e / (CT * 3);
            int r   = e % (CT * 3);
            int col = r % CT, z = r / CT;
            *(bf16x8*)(xh_lds + buf * BUF + col * KSTR + 104 + z * 8) = z8;
            *(bf16x8*)(xl_lds + buf * BUF + col * KSTR + 104 + z * 8) = z8;
        }
    }

    // --- prologue: stage chunk 0 into buffer 0 ------------------------------
#pragma unroll
    for (int i = 0; i < SPT; i++) if (sv[i]) {
        int nn = NN[sj[i] * SITES + s0base + scol[i]];
        if constexpr (NCIN == 1) {
            float v = prev[(size_t)b * SITES + nn];
            __bf16 hi = (__bf16)v;
            xh_lds[scol[i] * KSTR + sj[i]] = hi;
            xl_lds[scol[i] * KSTR + sj[i]] = (__bf16)(v - (float)hi);
        } else {
            const float4* p4 = (const float4*)(prev + ((size_t)(b * SITES + nn)) * 8);
            float4 u0 = p4[0], u1 = p4[1];
            float v[8] = {u0.x, u0.y, u0.z, u0.w, u1.x, u1.y, u1.z, u1.w};
            bf16x8 hv, lv;
#pragma unroll
            for (int c8 = 0; c8 < 8; c8++) {
                __bf16 hi = (__bf16)v[c8];
                hv[c8] = hi;
                lv[c8] = (__bf16)(v[c8] - (float)hi);
            }
            *(bf16x8*)(xh_lds + scol[i] * KSTR + sj[i] * 8) = hv;
            *(bf16x8*)(xl_lds + scol[i] * KSTR + sj[i] * 8) = lv;
        }
    }

    // NN for chunk 1 (issued before the barrier, consumed next iteration)
    int nnA[SPT];
    if (CHUNKS > 1) {
        const int s1 = s0base + CT;
#pragma unroll
        for (int i = 0; i < SPT; i++)
            nnA[i] = sv[i] ? NN[sj[i] * SITES + s1 + scol[i]] : 0;
    }
    __syncthreads();

    const int wave_mt0 = (wave / NWN) * MT_W;
    const int wave_nt0 = (wave % NWN) * NT_W;
    const int o_g      = (wave_mt0 * 16) / NGRP;
    const float bo     = bias[o_g];

#pragma unroll 1
    for (int c = 0; c < CHUNKS; c++) {
        const int cur = c & 1;

        // --- issue gather loads for chunk c+1 (uses prefetched nnA) ---------
        float4 ga[SPT], gb[SPT];
        float  g1[SPT];
        if (c + 1 < CHUNKS) {
#pragma unroll
            for (int i = 0; i < SPT; i++) if (sv[i]) {
                if constexpr (NCIN == 1) {
                    g1[i] = prev[(size_t)b * SITES + nnA[i]];
                } else {
                    const float4* p4 =
                        (const float4*)(prev + ((size_t)(b * SITES + nnA[i])) * 8);
                    ga[i] = p4[0];
                    gb[i] = p4[1];
                }
            }
        }
        // --- issue NN loads for chunk c+2 -----------------------------------
        int nnB[SPT];
        if (c + 2 < CHUNKS) {
            const int s2 = s0base + (c + 2) * CT;
#pragma unroll
            for (int i = 0; i < SPT; i++)
                nnB[i] = sv[i] ? NN[sj[i] * SITES + s2 + scol[i]] : 0;
        }

        // --- compute chunk c from buffer cur --------------------------------
        const __bf16* xh = xh_lds + cur * BUF;
        const __bf16* xl = xl_lds + cur * BUF;

        f32x4 acc[MT_W][NT_W];
#pragma unroll
        for (int mt = 0; mt < MT_W; mt++)
#pragma unroll
            for (int nt = 0; nt < NT_W; nt++) acc[mt][nt] = (f32x4){0.f, 0.f, 0.f, 0.f};

#pragma unroll
        for (int kt = 0; kt < KT; kt++) {
            const int koff = kt * 32 + quad * 8;
            bf16x8 ah[MT_W], al[MT_W], bh[NT_W], bl[NT_W];
#pragma unroll
            for (int mt = 0; mt < MT_W; mt++) {
                int row = (wave_mt0 + mt) * 16 + m16;
                ah[mt] = *(const bf16x8*)(Wh + (size_t)row * KPAD + koff);
                al[mt] = *(const bf16x8*)(Wl + (size_t)row * KPAD + koff);
            }
#pragma unroll
            for (int nt = 0; nt < NT_W; nt++) {
                int cbase = ((wave_nt0 + nt) * 16 + m16) * KSTR + koff;
                bh[nt] = *(const bf16x8*)(xh + cbase);
                bl[nt] = *(const bf16x8*)(xl + cbase);
            }
#pragma unroll
            for (int mt = 0; mt < MT_W; mt++)
#pragma unroll
                for (int nt = 0; nt < NT_W; nt++) {
                    acc[mt][nt] = __builtin_amdgcn_mfma_f32_16x16x32_bf16(
                        ah[mt], bh[nt], acc[mt][nt], 0, 0, 0);
                    acc[mt][nt] = __builtin_amdgcn_mfma_f32_16x16x32_bf16(
                        al[mt], bh[nt], acc[mt][nt], 0, 0, 0);
                    acc[mt][nt] = __builtin_amdgcn_mfma_f32_16x16x32_bf16(
                        ah[mt], bl[nt], acc[mt][nt], 0, 0, 0);
                }
        }

        // --- epilogue: softplus + group mean (one o per wave) ---------------
        const int s0c = s0base + c * CT;
#pragma unroll
        for (int nt = 0; nt < NT_W; nt++) {
            float s = 0.f;
#pragma unroll
            for (int mt = 0; mt < MT_W; mt++)
#pragma unroll
                for (int r = 0; r < 4; r++)
                    s += softplus_f(acc[mt][nt][r] + bo);
            s += __shfl_xor(s, 16);
            s += __shfl_xor(s, 32);
            if (quad == 0)
                out[((size_t)(b * SITES + s0c + (wave_nt0 + nt) * 16 + m16)) * NCTOT + o_g]
                    = s * (1.f / 48.f);
        }

        // --- write staged chunk c+1 into buffer cur^1 (T14 write-late) ------
        if (c + 1 < CHUNKS) {
            __bf16* dh = xh_lds + (cur ^ 1) * BUF;
            __bf16* dl = xl_lds + (cur ^ 1) * BUF;
#pragma unroll
            for (int i = 0; i < SPT; i++) if (sv[i]) {
                if constexpr (NCIN == 1) {
                    float v = g1[i];
                    __bf16 hi = (__bf16)v;
                    dh[scol[i] * KSTR + sj[i]] = hi;
                    dl[scol[i] * KSTR + sj[i]] = (__bf16)(v - (float)hi);
                } else {
                    float v[8] = {ga[i].x, ga[i].y, ga[i].z, ga[i].w,
                                  gb[i].x, gb[i].y, gb[i].z, gb[i].w};
                    bf16x8 hv, lv;
#pragma unroll
                    for (int c8 = 0; c8 < 8; c8++) {
                        __bf16 hi = (__bf16)v[c8];
                        hv[c8] = hi;
                        lv[c8] = (__bf16)(v[c8] - (float)hi);
                    }
                    *(bf16x8*)(dh + scol[i] * KSTR + sj[i] * 8) = hv;
                    *(bf16x8*)(dl + scol[i] * KSTR + sj[i] * 8) = lv;
                }
            }
#pragma unroll
            for (int i = 0; i < SPT; i++) nnA[i] = nnB[i];
        }
        __syncthreads();
    }
}

// ---------------------------------------------------------------------------
// Reduce stage A: per (b, s-chunk) block -> 3 partial sums
// ---------------------------------------------------------------------------
__global__ __launch_bounds__(256) void reduce_a(
    const float* __restrict__ A2, const int* __restrict__ NN,
    const int* __restrict__ s2sh, const float* __restrict__ sw,
    const float* __restrict__ Avc, float* __restrict__ partial)
{
    const int b = blockIdx.x >> 4;
    const int chunk = blockIdx.x & 15;
    const int tid = threadIdx.x;
    const int s = (chunk << 8) + tid;
    const float* a = A2 + (size_t)b * SITES;

    float y0 = 0.f, y1 = 0.f, y2 = 0.f;
#pragma unroll
    for (int n = 0; n < NGB; n++) {
        float v = a[NN[n * SITES + s]];
        y0 = fmaf(Avc[n],           v, y0);
        y1 = fmaf(Avc[NGB + n],     v, y1);
        y2 = fmaf(Avc[2 * NGB + n], v, y2);
    }
    const float wgt = sw[s2sh[s]];
    y0 *= wgt; y1 *= wgt; y2 *= wgt;

    __shared__ float red[3][256];
    red[0][tid] = y0; red[1][tid] = y1; red[2][tid] = y2;
    __syncthreads();
    for (int st = 128; st > 0; st >>= 1) {
        if (tid < st) {
            red[0][tid] += red[0][tid + st];
            red[1][tid] += red[1][tid + st];
            red[2][tid] += red[2][tid + st];
        }
        __syncthreads();
    }
    if (tid < 3) partial[(b * 16 + chunk) * 3 + tid] = red[tid][0];
}

__global__ __launch_bounds__(256) void reduce_b(
    const float* __restrict__ partial, float* __restrict__ out)
{
    int t = threadIdx.x;
    if (t < BATCH * 3) {
        int b = t / 3, d = t - b * 3;
        float s = 0.f;
        for (int c = 0; c < 16; c++) s += partial[(b * 16 + c) * 3 + d];
        out[t] = s * (1.f / (float)SITES);
    }
}

// ---------------------------------------------------------------------------
extern "C" void kernel_launch(void* const* d_in, const int* in_sizes, int n_in,
                              void* d_out, int out_size, void* d_ws, size_t ws_size,
                              hipStream_t stream)
{
    const float* InStates = (const float*)d_in[0];
    const float* Psi0     = (const float*)d_in[1];
    const float* bias0    = (const float*)d_in[2];
    const float* Psi1     = (const float*)d_in[3];
    const float* bias1    = (const float*)d_in[4];
    const float* Psi2     = (const float*)d_in[5];
    const float* bias2    = (const float*)d_in[6];
    const float* wtVC     = (const float*)d_in[7];
    const float* ShellW   = (const float*)d_in[8];
    const float* gdiags   = (const float*)d_in[9];
    const int*   GnnPerms = (const int*)d_in[10];
    const int*   NNSites  = (const int*)d_in[11];
    const int*   S2Sh     = (const int*)d_in[12];

    float*  ws   = (float*)d_ws;
    float*  Avc  = ws + OFF_AVC;
    int*    QC   = (int*)(ws + OFF_QCTR);   // 3 layers x 8 XCD queue counters
    __bf16* U    = (__bf16*)(ws + OFF_U);
    float*  A0   = ws + OFF_A0;      // (B,S,8) channel-last
    float*  A1   = ws + OFF_A1;      // (B,S,8) channel-last
    float*  A2   = ws + OFF_A0;      // (B,S) alias: A0 dead once L2 runs
    float*  PART = ws + OFF_PART;

    float* out = (float*)d_out;      // (64,3) f32

    hipMemsetAsync(ws, 0, 64 * sizeof(float), stream);   // Avc + queue counters
    precompute_kernel<<<272, 256, 0, stream>>>(Psi0, Psi1, Psi2, wtVC, gdiags,
                                               GnnPerms, ws);

    constexpr int CHUNKS = 8;
    constexpr int NBLK   = BATCH * (SITES / 64) / CHUNKS;   // 512 blocks

    // L0: K=13 pad 32, KSTR=40 (80B rows, stride 20 words -> 2-way free)
    layer_mfma<1, 8, 64, 32, 40, 8, 1, CHUNKS><<<NBLK, 512, 0, stream>>>(
        InStates, U + UW0H, U + UW0L, bias0, NNSites, QC + 0, A0);
    // L1: K=104 pad 128, KSTR=136 (272B rows, stride 68 words -> 2-way free)
    layer_mfma<8, 8, 64, 128, 136, 8, 1, CHUNKS><<<NBLK, 512, 0, stream>>>(
        A0, U + UW1H, U + UW1L, bias1, NNSites, QC + 8, A1);
    // L2: K=104 pad 128, M=48 (1 o), 4 waves split cols
    layer_mfma<8, 1, 64, 128, 136, 4, 4, CHUNKS><<<NBLK, 256, 0, stream>>>(
        A1, U + UW2H, U + UW2L, bias2, NNSites, QC + 16, A2);

    reduce_a<<<BATCH * 16, 256, 0, stream>>>(A2, NNSites, S2Sh, ShellW, Avc, PART);
    reduce_b<<<1, 256, 0, stream>>>(PART, out);
}

// Round 4
// 331.458 us; speedup vs baseline: 1.2200x; 1.2200x over previous
//
#include <hip/hip_runtime.h>
#include <hip/hip_bf16.h>

// Problem constants (SymNetDP): B=64, S=4096, NGB=13, NG=48, DIM=3, NCH={8,8,1}
#define BATCH 64
#define SITES 4096
#define NGB 13
#define NGRP 48
#define SDIM 3

typedef __bf16 bf16x8 __attribute__((ext_vector_type(8)));
typedef float  f32x4  __attribute__((ext_vector_type(4)));

// ---------------------------------------------------------------------------
// Workspace layout:
//   Avc  : 39 f32 (pad 64)                      @ float 0
//   U    : bf16 region, 135168 elems            @ float 64
//     W0H [384][32] 12288 | W0L @12288 | W1H [384][128] @24576 (49152) |
//     W1L @73728 | W2H [48][128] @122880 (6144) | W2L @129024
//   A0   : (B,S,8) channel-last, 2097152 f32    @ float 67648  (A2 aliases)
//   A1   : (B,S,8) channel-last, 2097152 f32    @ float 2164800
//   PART : (64,16,3) 3072                       @ float 4261952
// K-packing for NCIN=8 layers: k = j*8 + c  (site's 8 channels contiguous).
// ---------------------------------------------------------------------------
#define OFF_AVC  0
#define OFF_U    64
#define OFF_A0   67648
#define OFF_A1   2164800
#define OFF_PART 4261952
#define UW0H 0
#define UW0L 12288
#define UW1H 24576
#define UW1L 73728
#define UW2H 122880
#define UW2L 129024

__device__ __forceinline__ float softplus_f(float h) {
    return fmaxf(h, 0.f) + __logf(1.f + __expf(-fabsf(h)));
}

// ---------------------------------------------------------------------------
// Precompute: rotated weights, bf16 hi/lo split, [row=o*48+g][KPAD] with
// k = j*8+c packing for K=104 layers (k = j for layer 0); plus Avc.
// ---------------------------------------------------------------------------
__global__ __launch_bounds__(256) void precompute_kernel(
    const float* __restrict__ Psi0, const float* __restrict__ Psi1,
    const float* __restrict__ Psi2, const float* __restrict__ wtVC,
    const float* __restrict__ gdiags, const int* __restrict__ perms,
    float* __restrict__ ws)
{
    float*  Avc = ws + OFF_AVC;
    __bf16* U   = (__bf16*)(ws + OFF_U);
    int t = blockIdx.x * 256 + threadIdx.x;
    if (t < 12288) {                       // W0: [384][32], k=j
        int k = t & 31, row = t >> 5;
        int o = row / NGRP, g = row - o * NGRP;
        float w = (k < NGB) ? Psi0[o * NGB + perms[g * NGB + k]] : 0.f;
        __bf16 hi = (__bf16)w;
        U[UW0H + t] = hi;
        U[UW0L + t] = (__bf16)(w - (float)hi);
    } else if (t < 61440) {                // W1: [384][128], k=j*8+c
        int u = t - 12288;
        int k = u & 127, row = u >> 7;
        int o = row / NGRP, g = row - o * NGRP;
        float w = 0.f;
        if (k < 104) { int j = k >> 3, c = k & 7;
                       w = Psi1[(o * 8 + c) * NGB + perms[g * NGB + j]]; }
        __bf16 hi = (__bf16)w;
        U[UW1H + u] = hi;
        U[UW1L + u] = (__bf16)(w - (float)hi);
    } else if (t < 67584) {                // W2: [48][128], k=j*8+c
        int u = t - 61440;
        int k = u & 127, g = u >> 7;
        float w = 0.f;
        if (k < 104) { int j = k >> 3, c = k & 7;
                       w = Psi2[c * NGB + perms[g * NGB + j]]; }
        __bf16 hi = (__bf16)w;
        U[UW2H + u] = hi;
        U[UW2L + u] = (__bf16)(w - (float)hi);
    } else if (t < 67584 + 39 * NGRP) {    // Avc
        int t2 = t - 67584;
        int g = t2 % NGRP, u = t2 / NGRP;
        int d = u / NGB, n = u % NGB;
        const int row = g * SDIM + d;
        float s = 0.f;
        for (int k = 0; k < NGRP * SDIM; k++) {
            int g2 = k / SDIM, d2 = k - g2 * SDIM;
            float p = wtVC[d2 * NGB + perms[g2 * NGB + n]];
            s = fmaf(gdiags[row * (NGRP * SDIM) + k], p, s);
        }
        atomicAdd(&Avc[u], s * (1.f / 48.f));
    }
}

// ---------------------------------------------------------------------------
// MFMA gconv layer (bf16x3 split), v13: PERSISTENT-LITE.
// v10-12 post-mortem: register-carried gather prefetch (16+ VGPRs live
// across the whole MFMA section) under the allocator's 64-VGPR choice
// spilled to scratch: ~240 MB of phantom WRITE_SIZE (~30x the real output)
// per dispatch = ~140 us of scratch traffic. v13 deletes ALL register-
// carried gather state: per iteration, compute chunk c from buffer c&1,
// epilogue, THEN gather+convert+ds_write chunk c+1 (consumed immediately;
// only nnA[SPT] int indices cross the compute phase). Gather latency is
// covered by the 2 resident blocks/CU (LDS 68KB -> exactly 2). Persistence
// still amortizes launches (512 vs 4096 blocks) and pad-zeroing.
// MFMA inner loop is product-major: dependent MFMAs on the same acc are
// 12 apart instead of back-to-back.
// ---------------------------------------------------------------------------
template<int NCIN, int NCTOT, int CT, int KPAD, int KSTR, int NWAVES, int NWN,
         int CHUNKS>
__global__ __launch_bounds__(NWAVES * 64) void layer_mfma(
    const float* __restrict__ prev,   // (B,S) if NCIN==1 else (B,S,8)
    const __bf16* __restrict__ Wh,    // [NCTOT*48][KPAD]
    const __bf16* __restrict__ Wl,
    const float* __restrict__ bias,   // (NCTOT,)
    const int*   __restrict__ NN,     // (13, S)
    float* __restrict__ out)          // (B,S,NCTOT) channel-last
{
    constexpr int NTHR   = NWAVES * 64;
    constexpr int M      = NCTOT * NGRP;
    constexpr int MTILES = M / 16, NTILES = CT / 16;
    constexpr int NWM    = NWAVES / NWN;
    constexpr int MT_W   = MTILES / NWM, NT_W = NTILES / NWN;
    constexpr int KT     = KPAD / 32;
    constexpr int GS     = NGB * CT;              // gathered sites per chunk
    constexpr int SPT    = (GS + NTHR - 1) / NTHR;
    constexpr int CPB    = SITES / CT;            // chunks per batch
    constexpr int BUF    = CT * KSTR;             // halfwords per LDS buffer
    constexpr int BPB    = CPB / CHUNKS;          // blocks per batch

    static_assert(MT_W * 16 == NGRP, "wave covers exactly one o");
    static_assert(NWM * MT_W == MTILES && NWN * NT_W == NTILES, "");
    static_assert((KPAD & 31) == 0 && (KSTR & 7) == 0, "");
    static_assert(CPB % CHUNKS == 0, "block stays within one batch");

    __shared__ __bf16 xh_lds[2 * BUF];
    __shared__ __bf16 xl_lds[2 * BUF];

    const int tid  = threadIdx.x;
    const int wave = tid >> 6, lane = tid & 63;
    const int m16  = lane & 15, quad = lane >> 4;

    const int bid    = blockIdx.x;
    const int b      = bid / BPB;
    const int octet  = bid % BPB;
    const int s0base = octet * (CHUNKS * CT);

    // --- per-thread staged-site slots (static decomposition) ----------------
    int sj[SPT], scol[SPT];
    bool sv[SPT];
#pragma unroll
    for (int i = 0; i < SPT; i++) {
        int site = tid + i * NTHR;
        sv[i] = (site < GS);
        int ss = sv[i] ? site : 0;
        sj[i] = ss / CT;
        scol[i] = ss % CT;
    }

    // staging of one site: load -> hi/lo split -> LDS write (consumed at once)
    auto stage_site = [&](int i, int nn, __bf16* dh, __bf16* dl) {
        if constexpr (NCIN == 1) {
            float v = prev[(size_t)b * SITES + nn];
            __bf16 hi = (__bf16)v;
            dh[scol[i] * KSTR + sj[i]] = hi;
            dl[scol[i] * KSTR + sj[i]] = (__bf16)(v - (float)hi);
        } else {
            const float4* p4 = (const float4*)(prev + ((size_t)(b * SITES + nn)) * 8);
            float4 u0 = p4[0], u1 = p4[1];
            float v[8] = {u0.x, u0.y, u0.z, u0.w, u1.x, u1.y, u1.z, u1.w};
            bf16x8 hv, lv;
#pragma unroll
            for (int c8 = 0; c8 < 8; c8++) {
                __bf16 hi = (__bf16)v[c8];
                hv[c8] = hi;
                lv[c8] = (__bf16)(v[c8] - (float)hi);
            }
            *(bf16x8*)(dh + scol[i] * KSTR + sj[i] * 8) = hv;
            *(bf16x8*)(dl + scol[i] * KSTR + sj[i] * 8) = lv;
        }
    };

    // --- zero the K-pad region of BOTH buffers once -------------------------
    if constexpr (NCIN == 1) {
        for (int e = tid; e < 2 * CT * (KPAD - NGB); e += NTHR) {
            int buf = e / (CT * (KPAD - NGB));
            int r   = e % (CT * (KPAD - NGB));
            int col = r / (KPAD - NGB), p = r % (KPAD - NGB);
            xh_lds[buf * BUF + col * KSTR + NGB + p] = (__bf16)0.f;
            xl_lds[buf * BUF + col * KSTR + NGB + p] = (__bf16)0.f;
        }
    } else {
        const bf16x8 z8 = {};
        for (int e = tid; e < 2 * CT * 3; e += NTHR) {
            int buf = e / (CT * 3);
            int r   = e % (CT * 3);
            int col = r % CT, z = r / CT;
            *(bf16x8*)(xh_lds + buf * BUF + col * KSTR + 104 + z * 8) = z8;
            *(bf16x8*)(xl_lds + buf * BUF + col * KSTR + 104 + z * 8) = z8;
        }
    }

    // --- prologue: stage chunk 0 into buffer 0; prefetch NN for chunk 1 -----
#pragma unroll
    for (int i = 0; i < SPT; i++) if (sv[i]) {
        int nn = NN[sj[i] * SITES + s0base + scol[i]];
        stage_site(i, nn, xh_lds, xl_lds);
    }
    int nnA[SPT];
    if (CHUNKS > 1) {
        const int s1 = s0base + CT;
#pragma unroll
        for (int i = 0; i < SPT; i++)
            nnA[i] = sv[i] ? NN[sj[i] * SITES + s1 + scol[i]] : 0;
    }
    __syncthreads();

    const int wave_mt0 = (wave / NWN) * MT_W;
    const int wave_nt0 = (wave % NWN) * NT_W;
    const int o_g      = (wave_mt0 * 16) / NGRP;
    const float bo     = bias[o_g];

#pragma unroll 1
    for (int c = 0; c < CHUNKS; c++) {
        const int cur = c & 1;
        const __bf16* xh = xh_lds + cur * BUF;
        const __bf16* xl = xl_lds + cur * BUF;

        // --- compute chunk c from buffer cur --------------------------------
        f32x4 acc[MT_W][NT_W];
#pragma unroll
        for (int mt = 0; mt < MT_W; mt++)
#pragma unroll
            for (int nt = 0; nt < NT_W; nt++) acc[mt][nt] = (f32x4){0.f, 0.f, 0.f, 0.f};

#pragma unroll
        for (int kt = 0; kt < KT; kt++) {
            const int koff = kt * 32 + quad * 8;
            bf16x8 ah[MT_W], al[MT_W], bh[NT_W], bl[NT_W];
#pragma unroll
            for (int mt = 0; mt < MT_W; mt++) {
                int row = (wave_mt0 + mt) * 16 + m16;
                ah[mt] = *(const bf16x8*)(Wh + (size_t)row * KPAD + koff);
                al[mt] = *(const bf16x8*)(Wl + (size_t)row * KPAD + koff);
            }
#pragma unroll
            for (int nt = 0; nt < NT_W; nt++) {
                int cbase = ((wave_nt0 + nt) * 16 + m16) * KSTR + koff;
                bh[nt] = *(const bf16x8*)(xh + cbase);
                bl[nt] = *(const bf16x8*)(xl + cbase);
            }
            // product-major: 12 independent MFMAs between same-acc reuse
#pragma unroll
            for (int mt = 0; mt < MT_W; mt++)
#pragma unroll
                for (int nt = 0; nt < NT_W; nt++)
                    acc[mt][nt] = __builtin_amdgcn_mfma_f32_16x16x32_bf16(
                        ah[mt], bh[nt], acc[mt][nt], 0, 0, 0);
#pragma unroll
            for (int mt = 0; mt < MT_W; mt++)
#pragma unroll
                for (int nt = 0; nt < NT_W; nt++)
                    acc[mt][nt] = __builtin_amdgcn_mfma_f32_16x16x32_bf16(
                        al[mt], bh[nt], acc[mt][nt], 0, 0, 0);
#pragma unroll
            for (int mt = 0; mt < MT_W; mt++)
#pragma unroll
                for (int nt = 0; nt < NT_W; nt++)
                    acc[mt][nt] = __builtin_amdgcn_mfma_f32_16x16x32_bf16(
                        ah[mt], bl[nt], acc[mt][nt], 0, 0, 0);
        }

        // --- epilogue: softplus + group mean (one o per wave) ---------------
        const int s0c = s0base + c * CT;
#pragma unroll
        for (int nt = 0; nt < NT_W; nt++) {
            float s = 0.f;
#pragma unroll
            for (int mt = 0; mt < MT_W; mt++)
#pragma unroll
                for (int r = 0; r < 4; r++)
                    s += softplus_f(acc[mt][nt][r] + bo);
            s += __shfl_xor(s, 16);
            s += __shfl_xor(s, 32);
            if (quad == 0)
                out[((size_t)(b * SITES + s0c + (wave_nt0 + nt) * 16 + m16)) * NCTOT + o_g]
                    = s * (1.f / 48.f);
        }

        // --- stage chunk c+1 into buffer cur^1 (indices prefetched) ---------
        if (c + 1 < CHUNKS) {
            __bf16* dh = xh_lds + (cur ^ 1) * BUF;
            __bf16* dl = xl_lds + (cur ^ 1) * BUF;
#pragma unroll
            for (int i = 0; i < SPT; i++) if (sv[i])
                stage_site(i, nnA[i], dh, dl);
            // prefetch NN indices for chunk c+2 (2 ints live across compute)
            if (c + 2 < CHUNKS) {
                const int s2 = s0base + (c + 2) * CT;
#pragma unroll
                for (int i = 0; i < SPT; i++)
                    nnA[i] = sv[i] ? NN[sj[i] * SITES + s2 + scol[i]] : 0;
            }
        }
        __syncthreads();
    }
}

// ---------------------------------------------------------------------------
// Reduce stage A: per (b, s-chunk) block -> 3 partial sums
// ---------------------------------------------------------------------------
__global__ __launch_bounds__(256) void reduce_a(
    const float* __restrict__ A2, const int* __restrict__ NN,
    const int* __restrict__ s2sh, const float* __restrict__ sw,
    const float* __restrict__ Avc, float* __restrict__ partial)
{
    const int b = blockIdx.x >> 4;
    const int chunk = blockIdx.x & 15;
    const int tid = threadIdx.x;
    const int s = (chunk << 8) + tid;
    const float* a = A2 + (size_t)b * SITES;

    float y0 = 0.f, y1 = 0.f, y2 = 0.f;
#pragma unroll
    for (int n = 0; n < NGB; n++) {
        float v = a[NN[n * SITES + s]];
        y0 = fmaf(Avc[n],           v, y0);
        y1 = fmaf(Avc[NGB + n],     v, y1);
        y2 = fmaf(Avc[2 * NGB + n], v, y2);
    }
    const float wgt = sw[s2sh[s]];
    y0 *= wgt; y1 *= wgt; y2 *= wgt;

    __shared__ float red[3][256];
    red[0][tid] = y0; red[1][tid] = y1; red[2][tid] = y2;
    __syncthreads();
    for (int st = 128; st > 0; st >>= 1) {
        if (tid < st) {
            red[0][tid] += red[0][tid + st];
            red[1][tid] += red[1][tid + st];
            red[2][tid] += red[2][tid + st];
        }
        __syncthreads();
    }
    if (tid < 3) partial[(b * 16 + chunk) * 3 + tid] = red[tid][0];
}

__global__ __launch_bounds__(256) void reduce_b(
    const float* __restrict__ partial, float* __restrict__ out)
{
    int t = threadIdx.x;
    if (t < BATCH * 3) {
        int b = t / 3, d = t - b * 3;
        float s = 0.f;
        for (int c = 0; c < 16; c++) s += partial[(b * 16 + c) * 3 + d];
        out[t] = s * (1.f / (float)SITES);
    }
}

// ---------------------------------------------------------------------------
extern "C" void kernel_launch(void* const* d_in, const int* in_sizes, int n_in,
                              void* d_out, int out_size, void* d_ws, size_t ws_size,
                              hipStream_t stream)
{
    const float* InStates = (const float*)d_in[0];
    const float* Psi0     = (const float*)d_in[1];
    const float* bias0    = (const float*)d_in[2];
    const float* Psi1     = (const float*)d_in[3];
    const float* bias1    = (const float*)d_in[4];
    const float* Psi2     = (const float*)d_in[5];
    const float* bias2    = (const float*)d_in[6];
    const float* wtVC     = (const float*)d_in[7];
    const float* ShellW   = (const float*)d_in[8];
    const float* gdiags   = (const float*)d_in[9];
    const int*   GnnPerms = (const int*)d_in[10];
    const int*   NNSites  = (const int*)d_in[11];
    const int*   S2Sh     = (const int*)d_in[12];

    float*  ws   = (float*)d_ws;
    float*  Avc  = ws + OFF_AVC;
    __bf16* U    = (__bf16*)(ws + OFF_U);
    float*  A0   = ws + OFF_A0;      // (B,S,8) channel-last
    float*  A1   = ws + OFF_A1;      // (B,S,8) channel-last
    float*  A2   = ws + OFF_A0;      // (B,S) alias: A0 dead once L2 runs
    float*  PART = ws + OFF_PART;

    float* out = (float*)d_out;      // (64,3) f32

    hipMemsetAsync(Avc, 0, 64 * sizeof(float), stream);
    precompute_kernel<<<272, 256, 0, stream>>>(Psi0, Psi1, Psi2, wtVC, gdiags,
                                               GnnPerms, ws);

    constexpr int CHUNKS = 8;
    constexpr int NBLK   = BATCH * (SITES / 64) / CHUNKS;   // 512 blocks

    // L0: K=13 pad 32, KSTR=40 (80B rows, stride 20 words -> 2-way free)
    layer_mfma<1, 8, 64, 32, 40, 8, 1, CHUNKS><<<NBLK, 512, 0, stream>>>(
        InStates, U + UW0H, U + UW0L, bias0, NNSites, A0);
    // L1: K=104 pad 128, KSTR=136 (272B rows, stride 68 words -> 2-way free)
    layer_mfma<8, 8, 64, 128, 136, 8, 1, CHUNKS><<<NBLK, 512, 0, stream>>>(
        A0, U + UW1H, U + UW1L, bias1, NNSites, A1);
    // L2: K=104 pad 128, M=48 (1 o), 4 waves split cols
    layer_mfma<8, 1, 64, 128, 136, 4, 4, CHUNKS><<<NBLK, 256, 0, stream>>>(
        A1, U + UW2H, U + UW2L, bias2, NNSites, A2);

    reduce_a<<<BATCH * 16, 256, 0, stream>>>(A2, NNSites, S2Sh, ShellW, Avc, PART);
    reduce_b<<<1, 256, 0, stream>>>(PART, out);
}